// Round 2
// baseline (169.664 us; speedup 1.0000x reference)
//
#include <hip/hip_runtime.h>
#include <hip/hip_bf16.h>

// Problem constants: B=8, N=256, D=300, P=128, V=50001
#define NB 8
#define NN 256
#define DD 300
#define PP 128
#define OFF_S (NB * NN * NN)            // 524288  start-head element offset
#define OFF_E (NB * NN * NN + NB * NN)  // 526336  end-head element offset

typedef unsigned short u16;

__device__ __forceinline__ float bf2f(u16 u) {
    union { unsigned int i; float f; } v;
    v.i = ((unsigned int)u) << 16;
    return v.f;
}
__device__ __forceinline__ u16 f2bf(float f) {
    union { float f; unsigned int i; } v;
    v.f = f;
    unsigned int lsb = (v.i >> 16) & 1u;
    v.i += 0x7fffu + lsb;   // round-to-nearest-even
    return (u16)(v.i >> 16);
}

template<bool BF>
__device__ __forceinline__ float4 ld4(const void* base, int idx) {
    if (BF) {
        ushort4 e = *(const ushort4*)((const u16*)base + idx);
        return make_float4(bf2f(e.x), bf2f(e.y), bf2f(e.z), bf2f(e.w));
    } else {
        return *(const float4*)((const float*)base + idx);
    }
}
template<bool BF>
__device__ __forceinline__ float ld1(const void* base, int idx) {
    return BF ? bf2f(((const u16*)base)[idx]) : ((const float*)base)[idx];
}
template<bool BF>
__device__ __forceinline__ void st1(void* base, int idx, float v) {
    if (BF) ((u16*)base)[idx] = f2bf(v);
    else    ((float*)base)[idx] = v;
}

// ---------------------------------------------------------------------------
// Detector: bf16 vs f32. Low u16 of each word: bf16 data -> a genuine bf16
// N(0,1) sample (in [2^-8, 256] w.p. ~99.7%); f32 data -> uniform mantissa
// bits (in range ~6%).
// ---------------------------------------------------------------------------
extern "C" __global__ void detect_kernel(const unsigned int* __restrict__ embU,
                                         int* __restrict__ flag) {
    int lane = threadIdx.x;  // 64 threads
    int cnt = 0;
    for (int i = lane; i < 256; i += 64) {
        unsigned int w = embU[i];
        union { unsigned int u; float f; } v;
        v.u = (w & 0xFFFFu) << 16;
        float a = fabsf(v.f);
        if (a == 0.f || (a >= 0.00390625f && a <= 256.f)) cnt++;
    }
    #pragma unroll
    for (int off = 32; off; off >>= 1) cnt += __shfl_down(cnt, off, 64);
    if (lane == 0) *flag = (cnt >= 128) ? 1 : 0;
}

// ---------------------------------------------------------------------------
// Kernel A: per-token features. 8 tokens/block, 256 thr = (p in [0,128)) x
// (k-half in {0,1}). Produces leftT [B][P][N], rightW [B*N][P] (f32 ws) and
// the start/end heads straight into d_out.
// ---------------------------------------------------------------------------
template<bool BF>
__device__ __forceinline__ void tok_body(
    const int* __restrict__ sent, const void* __restrict__ emb,
    const void* __restrict__ Wl,  const void* __restrict__ bl,
    const void* __restrict__ Wr,
    const void* __restrict__ Ws1, const void* __restrict__ bs1,
    const void* __restrict__ Ws2, const void* __restrict__ bs2,
    const void* __restrict__ We1, const void* __restrict__ be1,
    const void* __restrict__ We2, const void* __restrict__ be2,
    float* __restrict__ leftT, float* __restrict__ rightW,
    void* __restrict__ out,
    float (*sx)[304], float (*redS)[128], float (*redE)[128])
{
    const int tid = threadIdx.x;
    const int t0  = blockIdx.x * 8;

    // Stage 8 embedding rows (-> f32 LDS). 600 4-elem chunks.
    for (int c = tid; c < 600; c += 256) {
        int t = c / 75;
        int q = c - t * 75;
        int idx = sent[t0 + t];
        float4 f = ld4<BF>(emb, idx * DD + (q << 2));
        *(float4*)&sx[t][q << 2] = f;
    }
    __syncthreads();

    const int p     = tid >> 1;
    const int kh    = tid & 1;
    const int based = kh * 152;      // K=300 split into 152 + 148 (both %4==0)
    const int nch   = 38 - kh;

    float accL[8], accR[8], accS[8], accE[8];
    #pragma unroll
    for (int t = 0; t < 8; ++t) { accL[t]=0.f; accR[t]=0.f; accS[t]=0.f; accE[t]=0.f; }

    const int wbase = p * DD + based;

    for (int c = 0; c < nch; ++c) {
        const int d4 = c << 2;
        float4 a = ld4<BF>(Wl,  wbase + d4);
        float4 r = ld4<BF>(Wr,  wbase + d4);
        float4 s = ld4<BF>(Ws1, wbase + d4);
        float4 e = ld4<BF>(We1, wbase + d4);
        #pragma unroll
        for (int t = 0; t < 8; ++t) {
            float4 xv = *(const float4*)&sx[t][based + d4];  // LDS broadcast
            accL[t] = fmaf(xv.x, a.x, accL[t]);
            accL[t] = fmaf(xv.y, a.y, accL[t]);
            accL[t] = fmaf(xv.z, a.z, accL[t]);
            accL[t] = fmaf(xv.w, a.w, accL[t]);
            accR[t] = fmaf(xv.x, r.x, accR[t]);
            accR[t] = fmaf(xv.y, r.y, accR[t]);
            accR[t] = fmaf(xv.z, r.z, accR[t]);
            accR[t] = fmaf(xv.w, r.w, accR[t]);
            accS[t] = fmaf(xv.x, s.x, accS[t]);
            accS[t] = fmaf(xv.y, s.y, accS[t]);
            accS[t] = fmaf(xv.z, s.z, accS[t]);
            accS[t] = fmaf(xv.w, s.w, accS[t]);
            accE[t] = fmaf(xv.x, e.x, accE[t]);
            accE[t] = fmaf(xv.y, e.y, accE[t]);
            accE[t] = fmaf(xv.z, e.z, accE[t]);
            accE[t] = fmaf(xv.w, e.w, accE[t]);
        }
    }

    // Combine the two K-halves: lanes (2p, 2p+1) adjacent in the wave.
    #pragma unroll
    for (int t = 0; t < 8; ++t) {
        accL[t] += __shfl_xor(accL[t], 1, 64);
        accR[t] += __shfl_xor(accR[t], 1, 64);
        accS[t] += __shfl_xor(accS[t], 1, 64);
        accE[t] += __shfl_xor(accE[t], 1, 64);
    }

    if (kh == 0) {
        float blp  = ld1<BF>(bl,  p);
        float bs1p = ld1<BF>(bs1, p);
        float ws2p = ld1<BF>(Ws2, p);
        #pragma unroll
        for (int t = 0; t < 8; ++t) {
            int tg = t0 + t;
            int bb = tg >> 8;
            int jj = tg & 255;
            leftT[((size_t)bb * PP + p) * NN + jj] = accL[t] + blp;
            rightW[(size_t)tg * PP + p]            = accR[t];
            redS[t][p] = fmaxf(accS[t] + bs1p, 0.f) * ws2p;
        }
    } else {
        float be1p = ld1<BF>(be1, p);
        float we2p = ld1<BF>(We2, p);
        #pragma unroll
        for (int t = 0; t < 8; ++t) {
            redE[t][p] = fmaxf(accE[t] + be1p, 0.f) * we2p;
        }
    }
    __syncthreads();

    // start/end reduction over p: 32 lanes per token.
    const int t = tid >> 5;
    const int l = tid & 31;
    float vs = redS[t][l] + redS[t][l + 32] + redS[t][l + 64] + redS[t][l + 96];
    float ve = redE[t][l] + redE[t][l + 32] + redE[t][l + 64] + redE[t][l + 96];
    #pragma unroll
    for (int off = 16; off; off >>= 1) {
        vs += __shfl_down(vs, off, 32);
        ve += __shfl_down(ve, off, 32);
    }
    if (l == 0) {
        st1<BF>(out, OFF_S + t0 + t, vs + ld1<BF>(bs2, 0));
        st1<BF>(out, OFF_E + t0 + t, ve + ld1<BF>(be2, 0));
    }
}

extern "C" __global__ void __launch_bounds__(256)
tok_kernel(const int* __restrict__ sent, const void* __restrict__ emb,
           const void* __restrict__ Wl,  const void* __restrict__ bl,
           const void* __restrict__ Wr,
           const void* __restrict__ Ws1, const void* __restrict__ bs1,
           const void* __restrict__ Ws2, const void* __restrict__ bs2,
           const void* __restrict__ We1, const void* __restrict__ be1,
           const void* __restrict__ We2, const void* __restrict__ be2,
           float* __restrict__ leftT, float* __restrict__ rightW,
           void* __restrict__ out, const int* __restrict__ flag)
{
    __shared__ float sx[8][304];
    __shared__ float redS[8][128];
    __shared__ float redE[8][128];
    if (*flag) {
        tok_body<true >(sent, emb, Wl, bl, Wr, Ws1, bs1, Ws2, bs2,
                        We1, be1, We2, be2, leftT, rightW, out, sx, redS, redE);
    } else {
        tok_body<false>(sent, emb, Wl, bl, Wr, Ws1, bs1, Ws2, bs2,
                        We1, be1, We2, be2, leftT, rightW, out, sx, redS, redE);
    }
}

// ---------------------------------------------------------------------------
// Kernel B: bigram[b,i,j] = sum_p relu(left[b,j,p] + right[b,i,p]) * Wo[p] + bo
// ---------------------------------------------------------------------------
extern "C" __global__ void __launch_bounds__(256)
big_kernel(const float* __restrict__ leftT, const float* __restrict__ rightW,
           const void* __restrict__ Wo, const void* __restrict__ bo,
           void* __restrict__ outB, const int* __restrict__ flag)
{
    __shared__ float sR[4][128];
    __shared__ float sWo[128];
    const int  tid = threadIdx.x;
    const int  b   = blockIdx.x >> 6;
    const int  i0  = (blockIdx.x & 63) << 2;
    const bool bf  = (*flag != 0);

    if (tid < 128) sWo[tid] = bf ? bf2f(((const u16*)Wo)[tid])
                                 : ((const float*)Wo)[tid];
    for (int c = tid; c < 512; c += 256) {
        int i = c >> 7, pp = c & 127;
        sR[i][pp] = rightW[((size_t)(b * NN + i0 + i)) * PP + pp];
    }
    __syncthreads();

    const int j = tid;
    const float* lp = leftT + (size_t)b * PP * NN + j;
    float acc0 = 0.f, acc1 = 0.f, acc2 = 0.f, acc3 = 0.f;
    #pragma unroll 8
    for (int pth = 0; pth < 128; ++pth) {
        float lv = lp[pth * NN];          // coalesced across j
        float wo = sWo[pth];
        acc0 = fmaf(fmaxf(lv + sR[0][pth], 0.f), wo, acc0);
        acc1 = fmaf(fmaxf(lv + sR[1][pth], 0.f), wo, acc1);
        acc2 = fmaf(fmaxf(lv + sR[2][pth], 0.f), wo, acc2);
        acc3 = fmaf(fmaxf(lv + sR[3][pth], 0.f), wo, acc3);
    }
    float bov = bf ? bf2f(((const u16*)bo)[0]) : ((const float*)bo)[0];
    size_t ob = ((size_t)(b * NN + i0)) * NN + j;
    if (bf) {
        u16* o = (u16*)outB;
        o[ob]          = f2bf(acc0 + bov);
        o[ob + NN]     = f2bf(acc1 + bov);
        o[ob + 2 * NN] = f2bf(acc2 + bov);
        o[ob + 3 * NN] = f2bf(acc3 + bov);
    } else {
        float* o = (float*)outB;
        o[ob]          = acc0 + bov;
        o[ob + NN]     = acc1 + bov;
        o[ob + 2 * NN] = acc2 + bov;
        o[ob + 3 * NN] = acc3 + bov;
    }
}

extern "C" void kernel_launch(void* const* d_in, const int* in_sizes, int n_in,
                              void* d_out, int out_size, void* d_ws, size_t ws_size,
                              hipStream_t stream) {
    const int*  sent = (const int*)d_in[0];
    const void* emb  = d_in[1];
    const void* Wl   = d_in[2];
    const void* bl   = d_in[3];
    const void* Wr   = d_in[4];
    const void* Wo   = d_in[5];
    const void* bo   = d_in[6];
    const void* Ws1  = d_in[7];
    const void* bs1  = d_in[8];
    const void* Ws2  = d_in[9];
    const void* bs2  = d_in[10];
    const void* We1  = d_in[11];
    const void* be1  = d_in[12];
    const void* We2  = d_in[13];
    const void* be2  = d_in[14];

    // Workspace: [flag 4B, pad to 1KB][leftT 1MB f32][rightW 1MB f32]
    int*   flag   = (int*)d_ws;
    float* leftT  = (float*)((char*)d_ws + 1024);
    float* rightW = leftT + (size_t)NB * PP * NN;

    hipLaunchKernelGGL(detect_kernel, dim3(1), dim3(64), 0, stream,
                       (const unsigned int*)emb, flag);
    hipLaunchKernelGGL(tok_kernel, dim3(256), dim3(256), 0, stream,
                       sent, emb, Wl, bl, Wr, Ws1, bs1, Ws2, bs2,
                       We1, be1, We2, be2, leftT, rightW, d_out, flag);
    hipLaunchKernelGGL(big_kernel, dim3(512), dim3(256), 0, stream,
                       leftT, rightW, Wo, bo, d_out, flag);
}